// Round 8
// baseline (1365.291 us; speedup 1.0000x reference)
//
#include <hip/hip_runtime.h>
#include <math.h>

#ifndef M_PI
#define M_PI 3.14159265358979323846
#endif

#define LEN   4096
#define NB    32
#define NH    64
#define NF    2048   // modes stored (bins 0..2047)
#define NLAYER 4

__device__ __forceinline__ float2 cmul(float2 a, float2 b) {
    return make_float2(a.x*b.x - a.y*b.y, a.x*b.y + a.y*b.x);
}

// async global -> LDS, 16 B per lane (dest = wave-uniform base + lane*16)
__device__ __forceinline__ void gll16(const void* g, void* l) {
    __builtin_amdgcn_global_load_lds(
        (const __attribute__((address_space(1))) void*)g,
        (__attribute__((address_space(3))) void*)l, 16, 0, 0);
}

// ---------------------------------------------------------------------------
// twiddle table: tw[k] = exp(-2*pi*i*k/4096), k = 0..4095 (full circle)
__global__ __launch_bounds__(256) void fill_tw(float2* __restrict__ tw) {
    int k = blockIdx.x * 256 + threadIdx.x;
    if (k < 4096) {
        double ang = -2.0 * M_PI * (double)k / 4096.0;
        tw[k] = make_float2((float)cos(ang), (float)sin(ang));
    }
}

// ---------------------------------------------------------------------------
// in-register 16-point DIF FFT. Natural-order input z[n]; output Z[k] lands
// in z[BR16[k]] (4-bit reversal, compile-time). INV=true: conjugated twiddles.
#define BR16_INIT const int BR[16] = {0,8,4,12,2,10,6,14,1,9,5,13,3,11,7,15}

template<bool INV>
__device__ __forceinline__ void fft16(float2 z[16]) {
    const float S  = INV ? 1.0f : -1.0f;
    const float C1 = 0.9238795325112867f, S1 = 0.3826834323650898f;
    const float C2 = 0.7071067811865476f;
    const float2 W16[8] = {{1.f,0.f},{C1,S*S1},{C2,S*C2},{S1,S*C1},
                           {0.f,S},{-S1,S*C1},{-C2,S*C2},{-C1,S*S1}};
    const float2 W8[4]  = {{1.f,0.f},{C2,S*C2},{0.f,S},{-C2,S*C2}};
    #pragma unroll
    for (int i = 0; i < 8; ++i) {
        float2 u = z[i], v = z[i+8];
        z[i]   = make_float2(u.x+v.x, u.y+v.y);
        float2 d = make_float2(u.x-v.x, u.y-v.y);
        z[i+8] = cmul(d, W16[i]);
    }
    #pragma unroll
    for (int h = 0; h < 16; h += 8)
        #pragma unroll
        for (int i = 0; i < 4; ++i) {
            float2 u = z[h+i], v = z[h+i+4];
            z[h+i]   = make_float2(u.x+v.x, u.y+v.y);
            float2 d = make_float2(u.x-v.x, u.y-v.y);
            z[h+i+4] = cmul(d, W8[i]);
        }
    #pragma unroll
    for (int h = 0; h < 16; h += 4) {
        { float2 u = z[h],   v = z[h+2];
          z[h]   = make_float2(u.x+v.x, u.y+v.y);
          z[h+2] = make_float2(u.x-v.x, u.y-v.y); }
        { float2 u = z[h+1], v = z[h+3];
          z[h+1] = make_float2(u.x+v.x, u.y+v.y);
          float2 d = make_float2(u.x-v.x, u.y-v.y);
          z[h+3] = make_float2(-S*d.y, S*d.x); }      // d * (0,S)
    }
    #pragma unroll
    for (int h = 0; h < 16; h += 2) {
        float2 u = z[h], v = z[h+1];
        z[h]   = make_float2(u.x+v.x, u.y+v.y);
        z[h+1] = make_float2(u.x-v.x, u.y-v.y);
    }
}

// ---------------------------------------------------------------------------
// encoder
__global__ __launch_bounds__(256) void encoder_k(
        const float* __restrict__ x, const float* __restrict__ u,
        const float* __restrict__ ew, const float* __restrict__ eb,
        float* __restrict__ v) {
    int tid = blockIdx.x * 256 + threadIdx.x;
    int b = tid >> 12;
    int l = tid & (LEN - 1);
    float xv = x[(size_t)b * LEN + l];
    float u0 = u[((size_t)b * 3 + 0) * LEN + l];
    float u1 = u[((size_t)b * 3 + 1) * LEN + l];
    float u2 = u[((size_t)b * 3 + 2) * LEN + l];
    for (int h = 0; h < NH; ++h) {
        float a = eb[h] + ew[h*4+0]*xv + ew[h*4+1]*u0 + ew[h*4+2]*u1 + ew[h*4+3]*u2;
        v[((size_t)b * NH + h) * LEN + l] = a;
    }
}

// ---------------------------------------------------------------------------
// forward FFT, radix-16^3 four-step, REAL-PAIR PACKED (round-6 verified).
__global__ __launch_bounds__(256) void fft_fwd_k(
        const float* __restrict__ vin, float2* __restrict__ Xt,
        const float2* __restrict__ tw) {
    __shared__ float2 lds[4352];                 // 34816 B
    BR16_INIT;
    int p = blockIdx.x;                          // 0..1023
    const float* s1 = vin + (size_t)(2*p)   * LEN;
    const float* s2 = vin + (size_t)(2*p+1) * LEN;
    int t = threadIdx.x;                         // = b
    float2 z[16];
    #pragma unroll
    for (int a = 0; a < 16; ++a)
        z[a] = make_float2(s1[a*256 + t], s2[a*256 + t]);
    fft16<false>(z);
    #pragma unroll
    for (int r = 0; r < 16; ++r) {
        int ka = BR[r];
        lds[ka*256 + t] = cmul(z[r], tw[t*ka]);
    }
    __syncthreads();
    int ka = t >> 4, bp = t & 15;                // round-2 role (k_a, b')
    #pragma unroll
    for (int a2 = 0; a2 < 16; ++a2)
        z[a2] = lds[ka*256 + a2*16 + bp];        // b = a2*16 + b'
    __syncthreads();
    fft16<false>(z);
    #pragma unroll
    for (int r = 0; r < 16; ++r) {
        int kap = BR[r];
        lds[kap*272 + ka*17 + bp] = cmul(z[r], tw[16*bp*kap]);
    }
    __syncthreads();
    int kap2 = t >> 4, ka2 = t & 15;             // round-3 role (k_a', k_a)
    #pragma unroll
    for (int b2 = 0; b2 < 16; ++b2)
        z[b2] = lds[kap2*272 + ka2*17 + b2];
    __syncthreads();
    fft16<false>(z);
    #pragma unroll
    for (int r = 0; r < 16; ++r)
        lds[t + 256*BR[r]] = z[r];
    __syncthreads();
    float2* d1 = Xt + (size_t)(2*p)   * NF;
    float2* d2 = Xt + (size_t)(2*p+1) * NF;
    for (int j = 0; j < 8; ++j) {
        int f = t + j * 256;                     // 0..2047
        float2 Zf = lds[f];
        float2 Zm = lds[(4096 - f) & 4095];
        d1[f] = make_float2(0.5f * (Zf.x + Zm.x), 0.5f * (Zf.y - Zm.y));
        d2[f] = make_float2(0.5f * (Zf.y + Zm.y), 0.5f * (Zm.x - Zf.x));
    }
}

// ---------------------------------------------------------------------------
// inverse FFT, radix-16^3 four-step (round-6 verified), partial-spectra input.
__device__ __forceinline__ float2 load_partial(
        const float2* __restrict__ r2, const float2* __restrict__ r1,
        const float2* __restrict__ r0, int f) {
    float2 y = r2[f];
    if (f < 1024) {
        float2 q = r1[f]; y.x += q.x; y.y += q.y;
        if (f < 512) { float2 w = r0[f]; y.x += w.x; y.y += w.y; }
    }
    return y;
}

__global__ __launch_bounds__(256) void fft_inv_k(
        const float2* __restrict__ Y2, const float2* __restrict__ Y1,
        const float2* __restrict__ Y0, float* __restrict__ sout,
        const float2* __restrict__ tw,
        const float* __restrict__ sb0, const float* __restrict__ sb1,
        const float* __restrict__ sb2, int layer) {
    __shared__ float2 lds[4352];
    BR16_INIT;
    int p = blockIdx.x;                          // 0..1023
    int o = (2 * p) & (NH - 1);                  // even o
    const float2* r1_2 = Y2 + (size_t)(2*p)   * 2048;
    const float2* r2_2 = Y2 + (size_t)(2*p+1) * 2048;
    const float2* r1_1 = Y1 + (size_t)(2*p)   * 1024;
    const float2* r2_1 = Y1 + (size_t)(2*p+1) * 1024;
    const float2* r1_0 = Y0 + (size_t)(2*p)   * 512;
    const float2* r2_0 = Y0 + (size_t)(2*p+1) * 512;
    int t = threadIdx.x;
    float2 z[16];
    #pragma unroll
    for (int a = 0; a < 16; ++a) {
        int f = a * 256 + t;
        float2 zf;
        if (f < 2048) {
            float2 y1 = load_partial(r1_2, r1_1, r1_0, f);
            float2 y2 = load_partial(r2_2, r2_1, r2_0, f);
            if (f == 0) zf = make_float2(y1.x, y2.x);
            else        zf = make_float2(y1.x - y2.y, y1.y + y2.x);
        } else if (f == 2048) {
            zf = make_float2(0.0f, 0.0f);
        } else {
            int m = 4096 - f;                    // 1..2047
            float2 y1 = load_partial(r1_2, r1_1, r1_0, m);
            float2 y2 = load_partial(r2_2, r2_1, r2_0, m);
            zf = make_float2(y1.x + y2.y, y2.x - y1.y);  // conj(Y1)+i*conj(Y2)
        }
        z[a] = zf;
    }
    fft16<true>(z);
    #pragma unroll
    for (int r = 0; r < 16; ++r) {
        int ka = BR[r];
        float2 w = tw[t*ka]; w.y = -w.y;
        lds[ka*256 + t] = cmul(z[r], w);
    }
    __syncthreads();
    int ka = t >> 4, bp = t & 15;
    #pragma unroll
    for (int a2 = 0; a2 < 16; ++a2)
        z[a2] = lds[ka*256 + a2*16 + bp];
    __syncthreads();
    fft16<true>(z);
    #pragma unroll
    for (int r = 0; r < 16; ++r) {
        int kap = BR[r];
        float2 w = tw[16*bp*kap]; w.y = -w.y;
        lds[kap*272 + ka*17 + bp] = cmul(z[r], w);
    }
    __syncthreads();
    int kap2 = t >> 4, ka2 = t & 15;
    #pragma unroll
    for (int b2 = 0; b2 < 16; ++b2)
        z[b2] = lds[kap2*272 + ka2*17 + b2];
    fft16<true>(z);
    float bias1 = sb0[layer*NH+o]   + sb1[layer*NH+o]   + sb2[layer*NH+o];
    float bias2 = sb0[layer*NH+o+1] + sb1[layer*NH+o+1] + sb2[layer*NH+o+1];
    float* d1 = sout + (size_t)(2*p)   * LEN;
    float* d2 = sout + (size_t)(2*p+1) * LEN;
    const float sc = 1.0f / 4096.0f;
    #pragma unroll
    for (int r = 0; r < 16; ++r) {
        int l = t + 256 * BR[r];
        d1[l] = z[r].x * sc + bias1;
        d2[l] = z[r].y * sc + bias2;
    }
}

// ---------------------------------------------------------------------------
// spectral matmul v7: 3-deep ring of async-staged LDS buffers with COUNTED
// vmcnt (never drained to 0 in the loop). Per chunk:
//   s_waitcnt vmcnt(6)   -- oldest chunk landed; 2 chunks stay in flight
//   s_barrier            -- all 4 waves' DMAs for this chunk now complete
//   compute(ic)          -- ds_read + FMA from buf[ic%3]
//   s_barrier            -- nobody still reads buf[ic%3]
//   STAGE(ic+3)          -- overwrite it; ~2 chunks (~1500cy) to land
// Loads get ~1500 cyc to cover ~900 cyc HBM latency (R7's single-barrier
// structure gave them only ~500). Addressing identical to verified R7:
// linear LDS, X swizzled on the global-source side, W broadcast rows.
__global__ __launch_bounds__(256) void specmm_k(
        const float2* __restrict__ X,
        float2* __restrict__ Y2p, float2* __restrict__ Y1p, float2* __restrict__ Y0p,
        const float* __restrict__ w0, const float* __restrict__ w1,
        const float* __restrict__ w2, int layer) {
    __shared__ float2 Xb[3][1024];    // [buf][i4][b32][slot4][e2]  8 KB each
    __shared__ float2 Wb[3][512];     // [buf][i4][o16][slot4][e2]  4 KB each

    int n  = blockIdx.x;              // 0..1791
    int og = n & 3;
    int tile = n >> 2;                // 0..447
    int k, ftile;
    if (tile < 192)      { ftile = tile / 3;                 k = 2 - (tile % 3); }
    else if (tile < 320) { int q = tile - 192; ftile = 64  + (q >> 1); k = 2 - (q & 1); }
    else                 { ftile = 128 + (tile - 320);       k = 2; }
    int f0 = ftile * 8;

    const float2* wbp; float2* Yb; size_t mk;
    if (k == 2)      { wbp = (const float2*)w2 + (size_t)layer*NH*NH*2048; Yb = Y2p; mk = 2048; }
    else if (k == 1) { wbp = (const float2*)w1 + (size_t)layer*NH*NH*1024; Yb = Y1p; mk = 1024; }
    else             { wbp = (const float2*)w0 + (size_t)layer*NH*NH*512;  Yb = Y0p; mk = 512;  }

    int t  = threadIdx.x;
    int ff = t & 7;                   // compute: f offset 0..7
    int u  = t >> 3;                  // 0..31
    int b0  = (u & 7) * 4;            // compute: 4 b rows
    int oo0 = (u >> 3) * 4;           // compute: 4 o cols (== wave id)

    // staging roles: wave wv stages i-row wv of each 4-i chunk
    const int wv = t >> 6;            // wave 0..3
    const int ln = t & 63;
    const int bs = ln >> 2;           // 0..15 (b-sub / o)
    const int sl = ln & 3;            // slot 0..3

    float2 acc[4][4];
    #pragma unroll
    for (int bb = 0; bb < 4; ++bb)
        #pragma unroll
        for (int oo = 0; oo < 4; ++oo)
            acc[bb][oo] = make_float2(0.0f, 0.0f);

    // per-lane global source pointers (X pre-swizzled)
    const float2* gx0; const float2* gx1;
    {
        int b = bs;                                    // half 0
        int fp = sl ^ ((b >> 2) & 3);
        gx0 = X + ((size_t)b * NH + wv) * 2048 + f0 + 2*fp;
        b = 16 + bs;                                   // half 1
        fp = sl ^ ((b >> 2) & 3);
        gx1 = X + ((size_t)b * NH + wv) * 2048 + f0 + 2*fp;
    }
    const float2* gw = wbp + ((size_t)wv * NH + og*16 + bs) * mk + f0 + 2*sl;

    #define STAGE(ic_, nb_)                                                     \
    {                                                                           \
        gll16(gx0 + (size_t)(ic_)*4*2048, &Xb[nb_][(wv*32 +  0)*8]);            \
        gll16(gx1 + (size_t)(ic_)*4*2048, &Xb[nb_][(wv*32 + 16)*8]);            \
        gll16(gw  + (size_t)(ic_)*256*mk, &Wb[nb_][wv*128]);                    \
    }

    STAGE(0, 0);
    STAGE(1, 1);
    STAGE(2, 2);
    int cb = 0;
    for (int ic = 0; ic < 16; ++ic) {
        // counted wait: oldest chunk's 3 loads landed; rest stay in flight
        if (ic < 14)       asm volatile("s_waitcnt vmcnt(6)" ::: "memory");
        else if (ic == 14) asm volatile("s_waitcnt vmcnt(3)" ::: "memory");
        else               asm volatile("s_waitcnt vmcnt(0)" ::: "memory");
        __builtin_amdgcn_sched_barrier(0);
        __builtin_amdgcn_s_barrier();             // all waves' DMAs complete
        #pragma unroll
        for (int ii = 0; ii < 4; ++ii) {
            float2 xr[4], wr[4];
            #pragma unroll
            for (int bb = 0; bb < 4; ++bb) {
                int b = b0 + bb;
                int slot = (ff >> 1) ^ ((b >> 2) & 3);
                xr[bb] = Xb[cb][((ii*32 + b)*4 + slot)*2 + (ff & 1)];
            }
            #pragma unroll
            for (int oo = 0; oo < 4; ++oo)
                wr[oo] = Wb[cb][((ii*16 + oo0 + oo)*4 + (ff >> 1))*2 + (ff & 1)];
            #pragma unroll
            for (int bb = 0; bb < 4; ++bb)
                #pragma unroll
                for (int oo = 0; oo < 4; ++oo) {
                    acc[bb][oo].x += xr[bb].x * wr[oo].x - xr[bb].y * wr[oo].y;
                    acc[bb][oo].y += xr[bb].x * wr[oo].y + xr[bb].y * wr[oo].x;
                }
        }
        __builtin_amdgcn_s_barrier();             // buf[cb] free to overwrite
        if (ic < 13) STAGE(ic + 3, cb);           // lands ~2 chunks later
        cb = (cb == 2) ? 0 : cb + 1;
    }
    #undef STAGE

    // direct coalesced stores (lanes ff-contiguous -> 64B f-runs)
    #pragma unroll
    for (int bb = 0; bb < 4; ++bb)
        #pragma unroll
        for (int oo = 0; oo < 4; ++oo)
            Yb[((size_t)(b0 + bb) * NH + og * 16 + oo0 + oo) * mk + f0 + ff] = acc[bb][oo];
}

// ---------------------------------------------------------------------------
// fused conv1+gelu+conv2+residual: per (b,l), h stays in registers.
// Last layer: fuse the decoder (dot with dec_w) and write out directly.
__global__ __launch_bounds__(256) void conv_fused_k(
        const float* __restrict__ s,
        const float* __restrict__ c1w, const float* __restrict__ c1b,
        const float* __restrict__ c2w, const float* __restrict__ c2b,
        int layer, float* __restrict__ v,
        const float* __restrict__ dw, const float* __restrict__ db,
        float* __restrict__ out, int last) {
    int tid = blockIdx.x * 256 + threadIdx.x;
    int b = tid >> 12;
    int l = tid & (LEN - 1);
    float xr[NH];
    #pragma unroll
    for (int i = 0; i < NH; ++i) xr[i] = s[((size_t)b * NH + i) * LEN + l];
    const float* w1 = c1w + (size_t)layer * NH * NH;
    const float* b1 = c1b + layer * NH;
    const float* w2 = c2w + (size_t)layer * NH * NH;
    const float* b2 = c2b + layer * NH;
    float acc2[NH];
    #pragma unroll
    for (int o = 0; o < NH; ++o) acc2[o] = b2[o];
    for (int i = 0; i < NH; ++i) {               // not unrolled: keeps I-size sane
        float acc = b1[i];
        #pragma unroll
        for (int k = 0; k < NH; ++k) acc += w1[i * NH + k] * xr[k];
        float cc = 0.7978845608028654f * (acc + 0.044715f * acc * acc * acc);
        float e  = __expf(2.0f * cc);
        float th = 1.0f - 2.0f / (e + 1.0f);
        float h  = 0.5f * acc * (1.0f + th);
        #pragma unroll
        for (int o = 0; o < NH; ++o) acc2[o] += w2[o * NH + i] * h;
    }
    if (!last) {
        #pragma unroll
        for (int o = 0; o < NH; ++o) {
            size_t idx = ((size_t)b * NH + o) * LEN + l;
            v[idx] = v[idx] + acc2[o];
        }
    } else {
        float acc = db[0];
        #pragma unroll
        for (int o = 0; o < NH; ++o) {
            size_t idx = ((size_t)b * NH + o) * LEN + l;
            acc += dw[o] * (v[idx] + acc2[o]);
        }
        out[(size_t)b * LEN + l] = acc;
    }
}

// ---------------------------------------------------------------------------
extern "C" void kernel_launch(void* const* d_in, const int* in_sizes, int n_in,
                              void* d_out, int out_size, void* d_ws, size_t ws_size,
                              hipStream_t stream) {
    const float* u_in   = (const float*)d_in[0];
    const float* x_in   = (const float*)d_in[1];
    const float* enc_w  = (const float*)d_in[2];
    const float* enc_b  = (const float*)d_in[3];
    const float* dec_w  = (const float*)d_in[4];
    const float* dec_b  = (const float*)d_in[5];
    const float* conv1w = (const float*)d_in[6];
    const float* conv1b = (const float*)d_in[7];
    const float* conv2w = (const float*)d_in[8];
    const float* conv2b = (const float*)d_in[9];
    const float* sw0    = (const float*)d_in[10];
    const float* sb0    = (const float*)d_in[11];
    const float* sw1    = (const float*)d_in[12];
    const float* sb1    = (const float*)d_in[13];
    const float* sw2    = (const float*)d_in[14];
    const float* sb2    = (const float*)d_in[15];

    const size_t CPLX = (size_t)2048 * 2048;
    const size_t REAL = (size_t)NB * NH * LEN;
    char* base = (char*)d_ws;
    float2* tw   = (float2*)base;                // 4096 entries = 32768 B
    float2* bufA = (float2*)(base + 32768);      // X: [row][2048]
    float2* Y2p  = bufA + CPLX;                  // [row][2048]
    float2* Y1p  = Y2p + CPLX;                   // [row][1024]
    float2* Y0p  = Y1p + (size_t)2048 * 1024;    // [row][512]
    float*  sbuf = (float*)(Y0p + (size_t)2048 * 512);
    float*  vbuf = sbuf + REAL;
    size_t need = 32768 + (CPLX + CPLX + (size_t)2048*1024 + (size_t)2048*512) * sizeof(float2)
                + 2 * REAL * sizeof(float);
    if (ws_size < need) return;

    fill_tw<<<16, 256, 0, stream>>>(tw);
    encoder_k<<<(NB * LEN) / 256, 256, 0, stream>>>(x_in, u_in, enc_w, enc_b, vbuf);

    for (int l = 0; l < NLAYER; ++l) {
        fft_fwd_k  <<<NB * NH / 2, 256, 0, stream>>>(vbuf, bufA, tw);
        specmm_k   <<<1792, 256, 0, stream>>>(bufA, Y2p, Y1p, Y0p, sw0, sw1, sw2, l);
        fft_inv_k  <<<NB * NH / 2, 256, 0, stream>>>(Y2p, Y1p, Y0p, sbuf, tw,
                                                     sb0, sb1, sb2, l);
        conv_fused_k<<<(NB * LEN) / 256, 256, 0, stream>>>(sbuf, conv1w, conv1b,
                                                           conv2w, conv2b, l, vbuf,
                                                           dec_w, dec_b, (float*)d_out,
                                                           l == NLAYER - 1);
    }
}

// Round 9
// 1301.598 us; speedup vs baseline: 1.0489x; 1.0489x over previous
//
#include <hip/hip_runtime.h>
#include <math.h>

#ifndef M_PI
#define M_PI 3.14159265358979323846
#endif

#define LEN   4096
#define NB    32
#define NH    64
#define NF    2048   // modes stored (bins 0..2047)
#define NLAYER 4

__device__ __forceinline__ float2 cmul(float2 a, float2 b) {
    return make_float2(a.x*b.x - a.y*b.y, a.x*b.y + a.y*b.x);
}

// async global -> LDS, 16 B per lane (dest = wave-uniform base + lane*16)
__device__ __forceinline__ void gll16(const void* g, void* l) {
    __builtin_amdgcn_global_load_lds(
        (const __attribute__((address_space(1))) void*)g,
        (__attribute__((address_space(3))) void*)l, 16, 0, 0);
}

// ---------------------------------------------------------------------------
// twiddle table: tw[k] = exp(-2*pi*i*k/4096), k = 0..4095 (full circle)
__global__ __launch_bounds__(256) void fill_tw(float2* __restrict__ tw) {
    int k = blockIdx.x * 256 + threadIdx.x;
    if (k < 4096) {
        double ang = -2.0 * M_PI * (double)k / 4096.0;
        tw[k] = make_float2((float)cos(ang), (float)sin(ang));
    }
}

// ---------------------------------------------------------------------------
// in-register 16-point DIF FFT. Natural-order input z[n]; output Z[k] lands
// in z[BR16[k]] (4-bit reversal, compile-time). INV=true: conjugated twiddles.
#define BR16_INIT const int BR[16] = {0,8,4,12,2,10,6,14,1,9,5,13,3,11,7,15}

template<bool INV>
__device__ __forceinline__ void fft16(float2 z[16]) {
    const float S  = INV ? 1.0f : -1.0f;
    const float C1 = 0.9238795325112867f, S1 = 0.3826834323650898f;
    const float C2 = 0.7071067811865476f;
    const float2 W16[8] = {{1.f,0.f},{C1,S*S1},{C2,S*C2},{S1,S*C1},
                           {0.f,S},{-S1,S*C1},{-C2,S*C2},{-C1,S*S1}};
    const float2 W8[4]  = {{1.f,0.f},{C2,S*C2},{0.f,S},{-C2,S*C2}};
    #pragma unroll
    for (int i = 0; i < 8; ++i) {
        float2 u = z[i], v = z[i+8];
        z[i]   = make_float2(u.x+v.x, u.y+v.y);
        float2 d = make_float2(u.x-v.x, u.y-v.y);
        z[i+8] = cmul(d, W16[i]);
    }
    #pragma unroll
    for (int h = 0; h < 16; h += 8)
        #pragma unroll
        for (int i = 0; i < 4; ++i) {
            float2 u = z[h+i], v = z[h+i+4];
            z[h+i]   = make_float2(u.x+v.x, u.y+v.y);
            float2 d = make_float2(u.x-v.x, u.y-v.y);
            z[h+i+4] = cmul(d, W8[i]);
        }
    #pragma unroll
    for (int h = 0; h < 16; h += 4) {
        { float2 u = z[h],   v = z[h+2];
          z[h]   = make_float2(u.x+v.x, u.y+v.y);
          z[h+2] = make_float2(u.x-v.x, u.y-v.y); }
        { float2 u = z[h+1], v = z[h+3];
          z[h+1] = make_float2(u.x+v.x, u.y+v.y);
          float2 d = make_float2(u.x-v.x, u.y-v.y);
          z[h+3] = make_float2(-S*d.y, S*d.x); }      // d * (0,S)
    }
    #pragma unroll
    for (int h = 0; h < 16; h += 2) {
        float2 u = z[h], v = z[h+1];
        z[h]   = make_float2(u.x+v.x, u.y+v.y);
        z[h+1] = make_float2(u.x-v.x, u.y-v.y);
    }
}

// ---------------------------------------------------------------------------
// encoder
__global__ __launch_bounds__(256) void encoder_k(
        const float* __restrict__ x, const float* __restrict__ u,
        const float* __restrict__ ew, const float* __restrict__ eb,
        float* __restrict__ v) {
    int tid = blockIdx.x * 256 + threadIdx.x;
    int b = tid >> 12;
    int l = tid & (LEN - 1);
    float xv = x[(size_t)b * LEN + l];
    float u0 = u[((size_t)b * 3 + 0) * LEN + l];
    float u1 = u[((size_t)b * 3 + 1) * LEN + l];
    float u2 = u[((size_t)b * 3 + 2) * LEN + l];
    for (int h = 0; h < NH; ++h) {
        float a = eb[h] + ew[h*4+0]*xv + ew[h*4+1]*u0 + ew[h*4+2]*u1 + ew[h*4+3]*u2;
        v[((size_t)b * NH + h) * LEN + l] = a;
    }
}

// ---------------------------------------------------------------------------
// forward FFT, radix-16^3 four-step, REAL-PAIR PACKED (round-6 verified).
__global__ __launch_bounds__(256) void fft_fwd_k(
        const float* __restrict__ vin, float2* __restrict__ Xt,
        const float2* __restrict__ tw) {
    __shared__ float2 lds[4352];                 // 34816 B
    BR16_INIT;
    int p = blockIdx.x;                          // 0..1023
    const float* s1 = vin + (size_t)(2*p)   * LEN;
    const float* s2 = vin + (size_t)(2*p+1) * LEN;
    int t = threadIdx.x;                         // = b
    float2 z[16];
    #pragma unroll
    for (int a = 0; a < 16; ++a)
        z[a] = make_float2(s1[a*256 + t], s2[a*256 + t]);
    fft16<false>(z);
    #pragma unroll
    for (int r = 0; r < 16; ++r) {
        int ka = BR[r];
        lds[ka*256 + t] = cmul(z[r], tw[t*ka]);
    }
    __syncthreads();
    int ka = t >> 4, bp = t & 15;                // round-2 role (k_a, b')
    #pragma unroll
    for (int a2 = 0; a2 < 16; ++a2)
        z[a2] = lds[ka*256 + a2*16 + bp];        // b = a2*16 + b'
    __syncthreads();
    fft16<false>(z);
    #pragma unroll
    for (int r = 0; r < 16; ++r) {
        int kap = BR[r];
        lds[kap*272 + ka*17 + bp] = cmul(z[r], tw[16*bp*kap]);
    }
    __syncthreads();
    int kap2 = t >> 4, ka2 = t & 15;             // round-3 role (k_a', k_a)
    #pragma unroll
    for (int b2 = 0; b2 < 16; ++b2)
        z[b2] = lds[kap2*272 + ka2*17 + b2];
    __syncthreads();
    fft16<false>(z);
    #pragma unroll
    for (int r = 0; r < 16; ++r)
        lds[t + 256*BR[r]] = z[r];
    __syncthreads();
    float2* d1 = Xt + (size_t)(2*p)   * NF;
    float2* d2 = Xt + (size_t)(2*p+1) * NF;
    for (int j = 0; j < 8; ++j) {
        int f = t + j * 256;                     // 0..2047
        float2 Zf = lds[f];
        float2 Zm = lds[(4096 - f) & 4095];
        d1[f] = make_float2(0.5f * (Zf.x + Zm.x), 0.5f * (Zf.y - Zm.y));
        d2[f] = make_float2(0.5f * (Zf.y + Zm.y), 0.5f * (Zm.x - Zf.x));
    }
}

// ---------------------------------------------------------------------------
// inverse FFT, radix-16^3 four-step (round-6 verified), partial-spectra input.
__device__ __forceinline__ float2 load_partial(
        const float2* __restrict__ r2, const float2* __restrict__ r1,
        const float2* __restrict__ r0, int f) {
    float2 y = r2[f];
    if (f < 1024) {
        float2 q = r1[f]; y.x += q.x; y.y += q.y;
        if (f < 512) { float2 w = r0[f]; y.x += w.x; y.y += w.y; }
    }
    return y;
}

__global__ __launch_bounds__(256) void fft_inv_k(
        const float2* __restrict__ Y2, const float2* __restrict__ Y1,
        const float2* __restrict__ Y0, float* __restrict__ sout,
        const float2* __restrict__ tw,
        const float* __restrict__ sb0, const float* __restrict__ sb1,
        const float* __restrict__ sb2, int layer) {
    __shared__ float2 lds[4352];
    BR16_INIT;
    int p = blockIdx.x;                          // 0..1023
    int o = (2 * p) & (NH - 1);                  // even o
    const float2* r1_2 = Y2 + (size_t)(2*p)   * 2048;
    const float2* r2_2 = Y2 + (size_t)(2*p+1) * 2048;
    const float2* r1_1 = Y1 + (size_t)(2*p)   * 1024;
    const float2* r2_1 = Y1 + (size_t)(2*p+1) * 1024;
    const float2* r1_0 = Y0 + (size_t)(2*p)   * 512;
    const float2* r2_0 = Y0 + (size_t)(2*p+1) * 512;
    int t = threadIdx.x;
    float2 z[16];
    #pragma unroll
    for (int a = 0; a < 16; ++a) {
        int f = a * 256 + t;
        float2 zf;
        if (f < 2048) {
            float2 y1 = load_partial(r1_2, r1_1, r1_0, f);
            float2 y2 = load_partial(r2_2, r2_1, r2_0, f);
            if (f == 0) zf = make_float2(y1.x, y2.x);
            else        zf = make_float2(y1.x - y2.y, y1.y + y2.x);
        } else if (f == 2048) {
            zf = make_float2(0.0f, 0.0f);
        } else {
            int m = 4096 - f;                    // 1..2047
            float2 y1 = load_partial(r1_2, r1_1, r1_0, m);
            float2 y2 = load_partial(r2_2, r2_1, r2_0, m);
            zf = make_float2(y1.x + y2.y, y2.x - y1.y);  // conj(Y1)+i*conj(Y2)
        }
        z[a] = zf;
    }
    fft16<true>(z);
    #pragma unroll
    for (int r = 0; r < 16; ++r) {
        int ka = BR[r];
        float2 w = tw[t*ka]; w.y = -w.y;
        lds[ka*256 + t] = cmul(z[r], w);
    }
    __syncthreads();
    int ka = t >> 4, bp = t & 15;
    #pragma unroll
    for (int a2 = 0; a2 < 16; ++a2)
        z[a2] = lds[ka*256 + a2*16 + bp];
    __syncthreads();
    fft16<true>(z);
    #pragma unroll
    for (int r = 0; r < 16; ++r) {
        int kap = BR[r];
        float2 w = tw[16*bp*kap]; w.y = -w.y;
        lds[kap*272 + ka*17 + bp] = cmul(z[r], w);
    }
    __syncthreads();
    int kap2 = t >> 4, ka2 = t & 15;
    #pragma unroll
    for (int b2 = 0; b2 < 16; ++b2)
        z[b2] = lds[kap2*272 + ka2*17 + b2];
    fft16<true>(z);
    float bias1 = sb0[layer*NH+o]   + sb1[layer*NH+o]   + sb2[layer*NH+o];
    float bias2 = sb0[layer*NH+o+1] + sb1[layer*NH+o+1] + sb2[layer*NH+o+1];
    float* d1 = sout + (size_t)(2*p)   * LEN;
    float* d2 = sout + (size_t)(2*p+1) * LEN;
    const float sc = 1.0f / 4096.0f;
    #pragma unroll
    for (int r = 0; r < 16; ++r) {
        int l = t + 256 * BR[r];
        d1[l] = z[r].x * sc + bias1;
        d2[l] = z[r].y * sc + bias2;
    }
}

// ---------------------------------------------------------------------------
// spectral matmul v8 = v7 ring + XCD-RESIDENT SIBLING GROUPS.
// R8 post-mortem: all 4-12 siblings of an f-tile (4 og x 1-3 streams) read the
// SAME 128KB X slice, but adjacent blockIdx round-robins across the 8 XCDs
// (private L2s) -> the slice was fetched from HBM up to 8x (~200MB redundant).
// Remap: XCD x = n&7 owns heavy ftiles x*8+h (12 sibs), medium 64+x*8+m
// (8 sibs), light 128+x*16+l (4 sibs) -> all siblings share n&7 residue ->
// same XCD -> X slice fetched once per tile. 224 slots/XCD, grid 1792.
__global__ __launch_bounds__(256) void specmm_k(
        const float2* __restrict__ X,
        float2* __restrict__ Y2p, float2* __restrict__ Y1p, float2* __restrict__ Y0p,
        const float* __restrict__ w0, const float* __restrict__ w1,
        const float* __restrict__ w2, int layer) {
    __shared__ float2 Xb[3][1024];    // [buf][i4][b32][slot4][e2]  8 KB each
    __shared__ float2 Wb[3][512];     // [buf][i4][o16][slot4][e2]  4 KB each

    int n   = blockIdx.x;             // 0..1791
    int xcd = n & 7;                  // dispatch round-robin -> XCD id
    int s   = n >> 3;                 // slot within XCD, 0..223
    int k, ftile, og;
    if (s < 96) {            // heavy: f0 < 512, 3 streams x 4 og = 12 sibs
        int h = s / 12, sib = s - h * 12;
        ftile = xcd * 8 + h;                    // 0..63
        og = sib & 3;  k = sib >> 2;            // k in {0,1,2}
    } else if (s < 160) {    // medium: 512 <= f0 < 1024, 2 streams x 4 og
        int m = (s - 96) >> 3, sib = (s - 96) & 7;
        ftile = 64 + xcd * 8 + m;               // 64..127
        og = sib & 3;  k = 2 - (sib >> 2);      // k in {2,1}
    } else {                 // light: f0 >= 1024, 1 stream x 4 og
        int l2 = (s - 160) >> 2, sib = (s - 160) & 3;
        ftile = 128 + xcd * 16 + l2;            // 128..255
        og = sib;      k = 2;
    }
    int f0 = ftile * 8;

    const float2* wbp; float2* Yb; size_t mk;
    if (k == 2)      { wbp = (const float2*)w2 + (size_t)layer*NH*NH*2048; Yb = Y2p; mk = 2048; }
    else if (k == 1) { wbp = (const float2*)w1 + (size_t)layer*NH*NH*1024; Yb = Y1p; mk = 1024; }
    else             { wbp = (const float2*)w0 + (size_t)layer*NH*NH*512;  Yb = Y0p; mk = 512;  }

    int t  = threadIdx.x;
    int ff = t & 7;                   // compute: f offset 0..7
    int u  = t >> 3;                  // 0..31
    int b0  = (u & 7) * 4;            // compute: 4 b rows
    int oo0 = (u >> 3) * 4;           // compute: 4 o cols (== wave id)

    // staging roles: wave wv stages i-row wv of each 4-i chunk
    const int wv = t >> 6;            // wave 0..3
    const int ln = t & 63;
    const int bs = ln >> 2;           // 0..15 (b-sub / o)
    const int sl = ln & 3;            // slot 0..3

    float2 acc[4][4];
    #pragma unroll
    for (int bb = 0; bb < 4; ++bb)
        #pragma unroll
        for (int oo = 0; oo < 4; ++oo)
            acc[bb][oo] = make_float2(0.0f, 0.0f);

    // per-lane global source pointers (X pre-swizzled)
    const float2* gx0; const float2* gx1;
    {
        int b = bs;                                    // half 0
        int fp = sl ^ ((b >> 2) & 3);
        gx0 = X + ((size_t)b * NH + wv) * 2048 + f0 + 2*fp;
        b = 16 + bs;                                   // half 1
        fp = sl ^ ((b >> 2) & 3);
        gx1 = X + ((size_t)b * NH + wv) * 2048 + f0 + 2*fp;
    }
    const float2* gw = wbp + ((size_t)wv * NH + og*16 + bs) * mk + f0 + 2*sl;

    #define STAGE(ic_, nb_)                                                     \
    {                                                                           \
        gll16(gx0 + (size_t)(ic_)*4*2048, &Xb[nb_][(wv*32 +  0)*8]);            \
        gll16(gx1 + (size_t)(ic_)*4*2048, &Xb[nb_][(wv*32 + 16)*8]);            \
        gll16(gw  + (size_t)(ic_)*256*mk, &Wb[nb_][wv*128]);                    \
    }

    STAGE(0, 0);
    STAGE(1, 1);
    STAGE(2, 2);
    int cb = 0;
    for (int ic = 0; ic < 16; ++ic) {
        // counted wait: oldest chunk's 3 loads landed; rest stay in flight
        if (ic < 14)       asm volatile("s_waitcnt vmcnt(6)" ::: "memory");
        else if (ic == 14) asm volatile("s_waitcnt vmcnt(3)" ::: "memory");
        else               asm volatile("s_waitcnt vmcnt(0)" ::: "memory");
        __builtin_amdgcn_sched_barrier(0);
        __builtin_amdgcn_s_barrier();             // all waves' DMAs complete
        #pragma unroll
        for (int ii = 0; ii < 4; ++ii) {
            float2 xr[4], wr[4];
            #pragma unroll
            for (int bb = 0; bb < 4; ++bb) {
                int b = b0 + bb;
                int slot = (ff >> 1) ^ ((b >> 2) & 3);
                xr[bb] = Xb[cb][((ii*32 + b)*4 + slot)*2 + (ff & 1)];
            }
            #pragma unroll
            for (int oo = 0; oo < 4; ++oo)
                wr[oo] = Wb[cb][((ii*16 + oo0 + oo)*4 + (ff >> 1))*2 + (ff & 1)];
            #pragma unroll
            for (int bb = 0; bb < 4; ++bb)
                #pragma unroll
                for (int oo = 0; oo < 4; ++oo) {
                    acc[bb][oo].x += xr[bb].x * wr[oo].x - xr[bb].y * wr[oo].y;
                    acc[bb][oo].y += xr[bb].x * wr[oo].y + xr[bb].y * wr[oo].x;
                }
        }
        __builtin_amdgcn_s_barrier();             // buf[cb] free to overwrite
        if (ic < 13) STAGE(ic + 3, cb);           // lands ~2 chunks later
        cb = (cb == 2) ? 0 : cb + 1;
    }
    #undef STAGE

    // direct coalesced stores (lanes ff-contiguous -> 64B f-runs)
    #pragma unroll
    for (int bb = 0; bb < 4; ++bb)
        #pragma unroll
        for (int oo = 0; oo < 4; ++oo)
            Yb[((size_t)(b0 + bb) * NH + og * 16 + oo0 + oo) * mk + f0 + ff] = acc[bb][oo];
}

// ---------------------------------------------------------------------------
// fused conv1+gelu+conv2+residual: per (b,l), h stays in registers.
// Last layer: fuse the decoder (dot with dec_w) and write out directly.
__global__ __launch_bounds__(256) void conv_fused_k(
        const float* __restrict__ s,
        const float* __restrict__ c1w, const float* __restrict__ c1b,
        const float* __restrict__ c2w, const float* __restrict__ c2b,
        int layer, float* __restrict__ v,
        const float* __restrict__ dw, const float* __restrict__ db,
        float* __restrict__ out, int last) {
    int tid = blockIdx.x * 256 + threadIdx.x;
    int b = tid >> 12;
    int l = tid & (LEN - 1);
    float xr[NH];
    #pragma unroll
    for (int i = 0; i < NH; ++i) xr[i] = s[((size_t)b * NH + i) * LEN + l];
    const float* w1 = c1w + (size_t)layer * NH * NH;
    const float* b1 = c1b + layer * NH;
    const float* w2 = c2w + (size_t)layer * NH * NH;
    const float* b2 = c2b + layer * NH;
    float acc2[NH];
    #pragma unroll
    for (int o = 0; o < NH; ++o) acc2[o] = b2[o];
    for (int i = 0; i < NH; ++i) {               // not unrolled: keeps I-size sane
        float acc = b1[i];
        #pragma unroll
        for (int k = 0; k < NH; ++k) acc += w1[i * NH + k] * xr[k];
        float cc = 0.7978845608028654f * (acc + 0.044715f * acc * acc * acc);
        float e  = __expf(2.0f * cc);
        float th = 1.0f - 2.0f / (e + 1.0f);
        float h  = 0.5f * acc * (1.0f + th);
        #pragma unroll
        for (int o = 0; o < NH; ++o) acc2[o] += w2[o * NH + i] * h;
    }
    if (!last) {
        #pragma unroll
        for (int o = 0; o < NH; ++o) {
            size_t idx = ((size_t)b * NH + o) * LEN + l;
            v[idx] = v[idx] + acc2[o];
        }
    } else {
        float acc = db[0];
        #pragma unroll
        for (int o = 0; o < NH; ++o) {
            size_t idx = ((size_t)b * NH + o) * LEN + l;
            acc += dw[o] * (v[idx] + acc2[o]);
        }
        out[(size_t)b * LEN + l] = acc;
    }
}

// ---------------------------------------------------------------------------
extern "C" void kernel_launch(void* const* d_in, const int* in_sizes, int n_in,
                              void* d_out, int out_size, void* d_ws, size_t ws_size,
                              hipStream_t stream) {
    const float* u_in   = (const float*)d_in[0];
    const float* x_in   = (const float*)d_in[1];
    const float* enc_w  = (const float*)d_in[2];
    const float* enc_b  = (const float*)d_in[3];
    const float* dec_w  = (const float*)d_in[4];
    const float* dec_b  = (const float*)d_in[5];
    const float* conv1w = (const float*)d_in[6];
    const float* conv1b = (const float*)d_in[7];
    const float* conv2w = (const float*)d_in[8];
    const float* conv2b = (const float*)d_in[9];
    const float* sw0    = (const float*)d_in[10];
    const float* sb0    = (const float*)d_in[11];
    const float* sw1    = (const float*)d_in[12];
    const float* sb1    = (const float*)d_in[13];
    const float* sw2    = (const float*)d_in[14];
    const float* sb2    = (const float*)d_in[15];

    const size_t CPLX = (size_t)2048 * 2048;
    const size_t REAL = (size_t)NB * NH * LEN;
    char* base = (char*)d_ws;
    float2* tw   = (float2*)base;                // 4096 entries = 32768 B
    float2* bufA = (float2*)(base + 32768);      // X: [row][2048]
    float2* Y2p  = bufA + CPLX;                  // [row][2048]
    float2* Y1p  = Y2p + CPLX;                   // [row][1024]
    float2* Y0p  = Y1p + (size_t)2048 * 1024;    // [row][512]
    float*  sbuf = (float*)(Y0p + (size_t)2048 * 512);
    float*  vbuf = sbuf + REAL;
    size_t need = 32768 + (CPLX + CPLX + (size_t)2048*1024 + (size_t)2048*512) * sizeof(float2)
                + 2 * REAL * sizeof(float);
    if (ws_size < need) return;

    fill_tw<<<16, 256, 0, stream>>>(tw);
    encoder_k<<<(NB * LEN) / 256, 256, 0, stream>>>(x_in, u_in, enc_w, enc_b, vbuf);

    for (int l = 0; l < NLAYER; ++l) {
        fft_fwd_k  <<<NB * NH / 2, 256, 0, stream>>>(vbuf, bufA, tw);
        specmm_k   <<<1792, 256, 0, stream>>>(bufA, Y2p, Y1p, Y0p, sw0, sw1, sw2, l);
        fft_inv_k  <<<NB * NH / 2, 256, 0, stream>>>(Y2p, Y1p, Y0p, sbuf, tw,
                                                     sb0, sb1, sb2, l);
        conv_fused_k<<<(NB * LEN) / 256, 256, 0, stream>>>(sbuf, conv1w, conv1b,
                                                           conv2w, conv2b, l, vbuf,
                                                           dec_w, dec_b, (float*)d_out,
                                                           l == NLAYER - 1);
    }
}

// Round 10
// 1239.255 us; speedup vs baseline: 1.1017x; 1.0503x over previous
//
#include <hip/hip_runtime.h>
#include <math.h>

#ifndef M_PI
#define M_PI 3.14159265358979323846
#endif

#define LEN   4096
#define NB    32
#define NH    64
#define NF    2048   // modes stored (bins 0..2047)
#define NLAYER 4

__device__ __forceinline__ float2 cmul(float2 a, float2 b) {
    return make_float2(a.x*b.x - a.y*b.y, a.x*b.y + a.y*b.x);
}

// async global -> LDS, 16 B per lane (dest = wave-uniform base + lane*16)
__device__ __forceinline__ void gll16(const void* g, void* l) {
    __builtin_amdgcn_global_load_lds(
        (const __attribute__((address_space(1))) void*)g,
        (__attribute__((address_space(3))) void*)l, 16, 0, 0);
}

// ---------------------------------------------------------------------------
// twiddle table: tw[k] = exp(-2*pi*i*k/4096), k = 0..4095 (full circle)
__global__ __launch_bounds__(256) void fill_tw(float2* __restrict__ tw) {
    int k = blockIdx.x * 256 + threadIdx.x;
    if (k < 4096) {
        double ang = -2.0 * M_PI * (double)k / 4096.0;
        tw[k] = make_float2((float)cos(ang), (float)sin(ang));
    }
}

// ---------------------------------------------------------------------------
// conv2 weight transpose: w2t[l][i][o] = w2[l][o][i]  (4 layers x 64 x 64)
__global__ __launch_bounds__(256) void w2t_k(
        const float* __restrict__ w2, float* __restrict__ w2t) {
    int idx = blockIdx.x * 256 + threadIdx.x;    // 0..16383
    int l = idx >> 12;
    int r = idx & 4095;
    int o = r >> 6, i = r & 63;
    w2t[l * 4096 + i * 64 + o] = w2[idx];
}

// ---------------------------------------------------------------------------
// in-register 16-point DIF FFT. Natural-order input z[n]; output Z[k] lands
// in z[BR16[k]] (4-bit reversal, compile-time). INV=true: conjugated twiddles.
#define BR16_INIT const int BR[16] = {0,8,4,12,2,10,6,14,1,9,5,13,3,11,7,15}

template<bool INV>
__device__ __forceinline__ void fft16(float2 z[16]) {
    const float S  = INV ? 1.0f : -1.0f;
    const float C1 = 0.9238795325112867f, S1 = 0.3826834323650898f;
    const float C2 = 0.7071067811865476f;
    const float2 W16[8] = {{1.f,0.f},{C1,S*S1},{C2,S*C2},{S1,S*C1},
                           {0.f,S},{-S1,S*C1},{-C2,S*C2},{-C1,S*S1}};
    const float2 W8[4]  = {{1.f,0.f},{C2,S*C2},{0.f,S},{-C2,S*C2}};
    #pragma unroll
    for (int i = 0; i < 8; ++i) {
        float2 u = z[i], v = z[i+8];
        z[i]   = make_float2(u.x+v.x, u.y+v.y);
        float2 d = make_float2(u.x-v.x, u.y-v.y);
        z[i+8] = cmul(d, W16[i]);
    }
    #pragma unroll
    for (int h = 0; h < 16; h += 8)
        #pragma unroll
        for (int i = 0; i < 4; ++i) {
            float2 u = z[h+i], v = z[h+i+4];
            z[h+i]   = make_float2(u.x+v.x, u.y+v.y);
            float2 d = make_float2(u.x-v.x, u.y-v.y);
            z[h+i+4] = cmul(d, W8[i]);
        }
    #pragma unroll
    for (int h = 0; h < 16; h += 4) {
        { float2 u = z[h],   v = z[h+2];
          z[h]   = make_float2(u.x+v.x, u.y+v.y);
          z[h+2] = make_float2(u.x-v.x, u.y-v.y); }
        { float2 u = z[h+1], v = z[h+3];
          z[h+1] = make_float2(u.x+v.x, u.y+v.y);
          float2 d = make_float2(u.x-v.x, u.y-v.y);
          z[h+3] = make_float2(-S*d.y, S*d.x); }      // d * (0,S)
    }
    #pragma unroll
    for (int h = 0; h < 16; h += 2) {
        float2 u = z[h], v = z[h+1];
        z[h]   = make_float2(u.x+v.x, u.y+v.y);
        z[h+1] = make_float2(u.x-v.x, u.y-v.y);
    }
}

// ---------------------------------------------------------------------------
// encoder
__global__ __launch_bounds__(256) void encoder_k(
        const float* __restrict__ x, const float* __restrict__ u,
        const float* __restrict__ ew, const float* __restrict__ eb,
        float* __restrict__ v) {
    int tid = blockIdx.x * 256 + threadIdx.x;
    int b = tid >> 12;
    int l = tid & (LEN - 1);
    float xv = x[(size_t)b * LEN + l];
    float u0 = u[((size_t)b * 3 + 0) * LEN + l];
    float u1 = u[((size_t)b * 3 + 1) * LEN + l];
    float u2 = u[((size_t)b * 3 + 2) * LEN + l];
    for (int h = 0; h < NH; ++h) {
        float a = eb[h] + ew[h*4+0]*xv + ew[h*4+1]*u0 + ew[h*4+2]*u1 + ew[h*4+3]*u2;
        v[((size_t)b * NH + h) * LEN + l] = a;
    }
}

// ---------------------------------------------------------------------------
// forward FFT, radix-16^3 four-step, REAL-PAIR PACKED (round-6 verified).
__global__ __launch_bounds__(256) void fft_fwd_k(
        const float* __restrict__ vin, float2* __restrict__ Xt,
        const float2* __restrict__ tw) {
    __shared__ float2 lds[4352];                 // 34816 B
    BR16_INIT;
    int p = blockIdx.x;                          // 0..1023
    const float* s1 = vin + (size_t)(2*p)   * LEN;
    const float* s2 = vin + (size_t)(2*p+1) * LEN;
    int t = threadIdx.x;                         // = b
    float2 z[16];
    #pragma unroll
    for (int a = 0; a < 16; ++a)
        z[a] = make_float2(s1[a*256 + t], s2[a*256 + t]);
    fft16<false>(z);
    #pragma unroll
    for (int r = 0; r < 16; ++r) {
        int ka = BR[r];
        lds[ka*256 + t] = cmul(z[r], tw[t*ka]);
    }
    __syncthreads();
    int ka = t >> 4, bp = t & 15;                // round-2 role (k_a, b')
    #pragma unroll
    for (int a2 = 0; a2 < 16; ++a2)
        z[a2] = lds[ka*256 + a2*16 + bp];        // b = a2*16 + b'
    __syncthreads();
    fft16<false>(z);
    #pragma unroll
    for (int r = 0; r < 16; ++r) {
        int kap = BR[r];
        lds[kap*272 + ka*17 + bp] = cmul(z[r], tw[16*bp*kap]);
    }
    __syncthreads();
    int kap2 = t >> 4, ka2 = t & 15;             // round-3 role (k_a', k_a)
    #pragma unroll
    for (int b2 = 0; b2 < 16; ++b2)
        z[b2] = lds[kap2*272 + ka2*17 + b2];
    __syncthreads();
    fft16<false>(z);
    #pragma unroll
    for (int r = 0; r < 16; ++r)
        lds[t + 256*BR[r]] = z[r];
    __syncthreads();
    float2* d1 = Xt + (size_t)(2*p)   * NF;
    float2* d2 = Xt + (size_t)(2*p+1) * NF;
    for (int j = 0; j < 8; ++j) {
        int f = t + j * 256;                     // 0..2047
        float2 Zf = lds[f];
        float2 Zm = lds[(4096 - f) & 4095];
        d1[f] = make_float2(0.5f * (Zf.x + Zm.x), 0.5f * (Zf.y - Zm.y));
        d2[f] = make_float2(0.5f * (Zf.y + Zm.y), 0.5f * (Zm.x - Zf.x));
    }
}

// ---------------------------------------------------------------------------
// inverse FFT, radix-16^3 four-step (round-6 verified), partial-spectra input.
__device__ __forceinline__ float2 load_partial(
        const float2* __restrict__ r2, const float2* __restrict__ r1,
        const float2* __restrict__ r0, int f) {
    float2 y = r2[f];
    if (f < 1024) {
        float2 q = r1[f]; y.x += q.x; y.y += q.y;
        if (f < 512) { float2 w = r0[f]; y.x += w.x; y.y += w.y; }
    }
    return y;
}

__global__ __launch_bounds__(256) void fft_inv_k(
        const float2* __restrict__ Y2, const float2* __restrict__ Y1,
        const float2* __restrict__ Y0, float* __restrict__ sout,
        const float2* __restrict__ tw,
        const float* __restrict__ sb0, const float* __restrict__ sb1,
        const float* __restrict__ sb2, int layer) {
    __shared__ float2 lds[4352];
    BR16_INIT;
    int p = blockIdx.x;                          // 0..1023
    int o = (2 * p) & (NH - 1);                  // even o
    const float2* r1_2 = Y2 + (size_t)(2*p)   * 2048;
    const float2* r2_2 = Y2 + (size_t)(2*p+1) * 2048;
    const float2* r1_1 = Y1 + (size_t)(2*p)   * 1024;
    const float2* r2_1 = Y1 + (size_t)(2*p+1) * 1024;
    const float2* r1_0 = Y0 + (size_t)(2*p)   * 512;
    const float2* r2_0 = Y0 + (size_t)(2*p+1) * 512;
    int t = threadIdx.x;
    float2 z[16];
    #pragma unroll
    for (int a = 0; a < 16; ++a) {
        int f = a * 256 + t;
        float2 zf;
        if (f < 2048) {
            float2 y1 = load_partial(r1_2, r1_1, r1_0, f);
            float2 y2 = load_partial(r2_2, r2_1, r2_0, f);
            if (f == 0) zf = make_float2(y1.x, y2.x);
            else        zf = make_float2(y1.x - y2.y, y1.y + y2.x);
        } else if (f == 2048) {
            zf = make_float2(0.0f, 0.0f);
        } else {
            int m = 4096 - f;                    // 1..2047
            float2 y1 = load_partial(r1_2, r1_1, r1_0, m);
            float2 y2 = load_partial(r2_2, r2_1, r2_0, m);
            zf = make_float2(y1.x + y2.y, y2.x - y1.y);  // conj(Y1)+i*conj(Y2)
        }
        z[a] = zf;
    }
    fft16<true>(z);
    #pragma unroll
    for (int r = 0; r < 16; ++r) {
        int ka = BR[r];
        float2 w = tw[t*ka]; w.y = -w.y;
        lds[ka*256 + t] = cmul(z[r], w);
    }
    __syncthreads();
    int ka = t >> 4, bp = t & 15;
    #pragma unroll
    for (int a2 = 0; a2 < 16; ++a2)
        z[a2] = lds[ka*256 + a2*16 + bp];
    __syncthreads();
    fft16<true>(z);
    #pragma unroll
    for (int r = 0; r < 16; ++r) {
        int kap = BR[r];
        float2 w = tw[16*bp*kap]; w.y = -w.y;
        lds[kap*272 + ka*17 + bp] = cmul(z[r], w);
    }
    __syncthreads();
    int kap2 = t >> 4, ka2 = t & 15;
    #pragma unroll
    for (int b2 = 0; b2 < 16; ++b2)
        z[b2] = lds[kap2*272 + ka2*17 + b2];
    fft16<true>(z);
    float bias1 = sb0[layer*NH+o]   + sb1[layer*NH+o]   + sb2[layer*NH+o];
    float bias2 = sb0[layer*NH+o+1] + sb1[layer*NH+o+1] + sb2[layer*NH+o+1];
    float* d1 = sout + (size_t)(2*p)   * LEN;
    float* d2 = sout + (size_t)(2*p+1) * LEN;
    const float sc = 1.0f / 4096.0f;
    #pragma unroll
    for (int r = 0; r < 16; ++r) {
        int l = t + 256 * BR[r];
        d1[l] = z[r].x * sc + bias1;
        d2[l] = z[r].y * sc + bias2;
    }
}

// ---------------------------------------------------------------------------
// spectral matmul v8 (round-9 verified): v7 ring + XCD-resident sibling groups.
__global__ __launch_bounds__(256) void specmm_k(
        const float2* __restrict__ X,
        float2* __restrict__ Y2p, float2* __restrict__ Y1p, float2* __restrict__ Y0p,
        const float* __restrict__ w0, const float* __restrict__ w1,
        const float* __restrict__ w2, int layer) {
    __shared__ float2 Xb[3][1024];    // [buf][i4][b32][slot4][e2]  8 KB each
    __shared__ float2 Wb[3][512];     // [buf][i4][o16][slot4][e2]  4 KB each

    int n   = blockIdx.x;             // 0..1791
    int xcd = n & 7;                  // dispatch round-robin -> XCD id
    int s   = n >> 3;                 // slot within XCD, 0..223
    int k, ftile, og;
    if (s < 96) {            // heavy: f0 < 512, 3 streams x 4 og = 12 sibs
        int h = s / 12, sib = s - h * 12;
        ftile = xcd * 8 + h;                    // 0..63
        og = sib & 3;  k = sib >> 2;            // k in {0,1,2}
    } else if (s < 160) {    // medium: 512 <= f0 < 1024, 2 streams x 4 og
        int m = (s - 96) >> 3, sib = (s - 96) & 7;
        ftile = 64 + xcd * 8 + m;               // 64..127
        og = sib & 3;  k = 2 - (sib >> 2);      // k in {2,1}
    } else {                 // light: f0 >= 1024, 1 stream x 4 og
        int l2 = (s - 160) >> 2, sib = (s - 160) & 3;
        ftile = 128 + xcd * 16 + l2;            // 128..255
        og = sib;      k = 2;
    }
    int f0 = ftile * 8;

    const float2* wbp; float2* Yb; size_t mk;
    if (k == 2)      { wbp = (const float2*)w2 + (size_t)layer*NH*NH*2048; Yb = Y2p; mk = 2048; }
    else if (k == 1) { wbp = (const float2*)w1 + (size_t)layer*NH*NH*1024; Yb = Y1p; mk = 1024; }
    else             { wbp = (const float2*)w0 + (size_t)layer*NH*NH*512;  Yb = Y0p; mk = 512;  }

    int t  = threadIdx.x;
    int ff = t & 7;                   // compute: f offset 0..7
    int u  = t >> 3;                  // 0..31
    int b0  = (u & 7) * 4;            // compute: 4 b rows
    int oo0 = (u >> 3) * 4;           // compute: 4 o cols (== wave id)

    // staging roles: wave wv stages i-row wv of each 4-i chunk
    const int wv = t >> 6;            // wave 0..3
    const int ln = t & 63;
    const int bs = ln >> 2;           // 0..15 (b-sub / o)
    const int sl = ln & 3;            // slot 0..3

    float2 acc[4][4];
    #pragma unroll
    for (int bb = 0; bb < 4; ++bb)
        #pragma unroll
        for (int oo = 0; oo < 4; ++oo)
            acc[bb][oo] = make_float2(0.0f, 0.0f);

    // per-lane global source pointers (X pre-swizzled)
    const float2* gx0; const float2* gx1;
    {
        int b = bs;                                    // half 0
        int fp = sl ^ ((b >> 2) & 3);
        gx0 = X + ((size_t)b * NH + wv) * 2048 + f0 + 2*fp;
        b = 16 + bs;                                   // half 1
        fp = sl ^ ((b >> 2) & 3);
        gx1 = X + ((size_t)b * NH + wv) * 2048 + f0 + 2*fp;
    }
    const float2* gw = wbp + ((size_t)wv * NH + og*16 + bs) * mk + f0 + 2*sl;

    #define STAGE(ic_, nb_)                                                     \
    {                                                                           \
        gll16(gx0 + (size_t)(ic_)*4*2048, &Xb[nb_][(wv*32 +  0)*8]);            \
        gll16(gx1 + (size_t)(ic_)*4*2048, &Xb[nb_][(wv*32 + 16)*8]);            \
        gll16(gw  + (size_t)(ic_)*256*mk, &Wb[nb_][wv*128]);                    \
    }

    STAGE(0, 0);
    STAGE(1, 1);
    STAGE(2, 2);
    int cb = 0;
    for (int ic = 0; ic < 16; ++ic) {
        // counted wait: oldest chunk's 3 loads landed; rest stay in flight
        if (ic < 14)       asm volatile("s_waitcnt vmcnt(6)" ::: "memory");
        else if (ic == 14) asm volatile("s_waitcnt vmcnt(3)" ::: "memory");
        else               asm volatile("s_waitcnt vmcnt(0)" ::: "memory");
        __builtin_amdgcn_sched_barrier(0);
        __builtin_amdgcn_s_barrier();             // all waves' DMAs complete
        #pragma unroll
        for (int ii = 0; ii < 4; ++ii) {
            float2 xr[4], wr[4];
            #pragma unroll
            for (int bb = 0; bb < 4; ++bb) {
                int b = b0 + bb;
                int slot = (ff >> 1) ^ ((b >> 2) & 3);
                xr[bb] = Xb[cb][((ii*32 + b)*4 + slot)*2 + (ff & 1)];
            }
            #pragma unroll
            for (int oo = 0; oo < 4; ++oo)
                wr[oo] = Wb[cb][((ii*16 + oo0 + oo)*4 + (ff >> 1))*2 + (ff & 1)];
            #pragma unroll
            for (int bb = 0; bb < 4; ++bb)
                #pragma unroll
                for (int oo = 0; oo < 4; ++oo) {
                    acc[bb][oo].x += xr[bb].x * wr[oo].x - xr[bb].y * wr[oo].y;
                    acc[bb][oo].y += xr[bb].x * wr[oo].y + xr[bb].y * wr[oo].x;
                }
        }
        __builtin_amdgcn_s_barrier();             // buf[cb] free to overwrite
        if (ic < 13) STAGE(ic + 3, cb);           // lands ~2 chunks later
        cb = (cb == 2) ? 0 : cb + 1;
    }
    #undef STAGE

    // direct coalesced stores (lanes ff-contiguous -> 64B f-runs)
    #pragma unroll
    for (int bb = 0; bb < 4; ++bb)
        #pragma unroll
        for (int oo = 0; oo < 4; ++oo)
            Yb[((size_t)(b0 + bb) * NH + og * 16 + oo0 + oo) * mk + f0 + ff] = acc[bb][oo];
}

// ---------------------------------------------------------------------------
// fused conv1+gelu+conv2+residual v2:
//  - conv1 dot uses 4 partial accumulators (R0-R9 had a 64-deep serially
//    dependent FMA chain: ~256 exposed cycles per i at 2-3 waves/SIMD)
//  - conv2 reads PRE-TRANSPOSED w2t rows (contiguous, scalar-loadable as
//    s_load_dwordx16) instead of 64 stride-256B column gathers per i
// Last layer: decoder fused (dot with dec_w), writes out directly.
__global__ __launch_bounds__(256) void conv_fused_k(
        const float* __restrict__ s,
        const float* __restrict__ c1w, const float* __restrict__ c1b,
        const float* __restrict__ w2t, const float* __restrict__ c2b,
        int layer, float* __restrict__ v,
        const float* __restrict__ dw, const float* __restrict__ db,
        float* __restrict__ out, int last) {
    int tid = blockIdx.x * 256 + threadIdx.x;
    int b = tid >> 12;
    int l = tid & (LEN - 1);
    float xr[NH];
    #pragma unroll
    for (int i = 0; i < NH; ++i) xr[i] = s[((size_t)b * NH + i) * LEN + l];
    const float* w1 = c1w + (size_t)layer * NH * NH;
    const float* b1 = c1b + layer * NH;
    const float* w2 = w2t + (size_t)layer * NH * NH;   // [i][o] rows
    const float* b2 = c2b + layer * NH;
    float acc2[NH];
    #pragma unroll
    for (int o = 0; o < NH; ++o) acc2[o] = b2[o];
    for (int i = 0; i < NH; ++i) {               // not unrolled: keeps I-size sane
        const float* wr = w1 + i * NH;
        float a0 = 0.0f, a1 = 0.0f, a2 = 0.0f, a3 = 0.0f;
        #pragma unroll
        for (int k = 0; k < NH; k += 4) {
            a0 += wr[k]     * xr[k];
            a1 += wr[k + 1] * xr[k + 1];
            a2 += wr[k + 2] * xr[k + 2];
            a3 += wr[k + 3] * xr[k + 3];
        }
        float acc = b1[i] + ((a0 + a1) + (a2 + a3));
        float cc = 0.7978845608028654f * (acc + 0.044715f * acc * acc * acc);
        float e  = __expf(2.0f * cc);
        float th = 1.0f - 2.0f / (e + 1.0f);
        float h  = 0.5f * acc * (1.0f + th);
        const float* wc = w2 + i * NH;
        #pragma unroll
        for (int o = 0; o < NH; ++o) acc2[o] += wc[o] * h;
    }
    if (!last) {
        #pragma unroll
        for (int o = 0; o < NH; ++o) {
            size_t idx = ((size_t)b * NH + o) * LEN + l;
            v[idx] = v[idx] + acc2[o];
        }
    } else {
        float acc = db[0];
        #pragma unroll
        for (int o = 0; o < NH; ++o) {
            size_t idx = ((size_t)b * NH + o) * LEN + l;
            acc += dw[o] * (v[idx] + acc2[o]);
        }
        out[(size_t)b * LEN + l] = acc;
    }
}

// ---------------------------------------------------------------------------
extern "C" void kernel_launch(void* const* d_in, const int* in_sizes, int n_in,
                              void* d_out, int out_size, void* d_ws, size_t ws_size,
                              hipStream_t stream) {
    const float* u_in   = (const float*)d_in[0];
    const float* x_in   = (const float*)d_in[1];
    const float* enc_w  = (const float*)d_in[2];
    const float* enc_b  = (const float*)d_in[3];
    const float* dec_w  = (const float*)d_in[4];
    const float* dec_b  = (const float*)d_in[5];
    const float* conv1w = (const float*)d_in[6];
    const float* conv1b = (const float*)d_in[7];
    const float* conv2w = (const float*)d_in[8];
    const float* conv2b = (const float*)d_in[9];
    const float* sw0    = (const float*)d_in[10];
    const float* sb0    = (const float*)d_in[11];
    const float* sw1    = (const float*)d_in[12];
    const float* sb1    = (const float*)d_in[13];
    const float* sw2    = (const float*)d_in[14];
    const float* sb2    = (const float*)d_in[15];

    const size_t CPLX = (size_t)2048 * 2048;
    const size_t REAL = (size_t)NB * NH * LEN;
    char* base = (char*)d_ws;
    float2* tw   = (float2*)base;                // 4096 entries = 32768 B
    float2* bufA = (float2*)(base + 32768);      // X: [row][2048]
    float2* Y2p  = bufA + CPLX;                  // [row][2048]
    float2* Y1p  = Y2p + CPLX;                   // [row][1024]
    float2* Y0p  = Y1p + (size_t)2048 * 1024;    // [row][512]
    float*  sbuf = (float*)(Y0p + (size_t)2048 * 512);
    float*  vbuf = sbuf + REAL;
    float*  w2tb = vbuf + REAL;                  // transposed conv2 weights, 64 KB
    size_t need = 32768 + (CPLX + CPLX + (size_t)2048*1024 + (size_t)2048*512) * sizeof(float2)
                + 2 * REAL * sizeof(float) + (size_t)NLAYER*NH*NH*sizeof(float);
    if (ws_size < need) return;

    fill_tw<<<16, 256, 0, stream>>>(tw);
    w2t_k<<<64, 256, 0, stream>>>(conv2w, w2tb);
    encoder_k<<<(NB * LEN) / 256, 256, 0, stream>>>(x_in, u_in, enc_w, enc_b, vbuf);

    for (int l = 0; l < NLAYER; ++l) {
        fft_fwd_k  <<<NB * NH / 2, 256, 0, stream>>>(vbuf, bufA, tw);
        specmm_k   <<<1792, 256, 0, stream>>>(bufA, Y2p, Y1p, Y0p, sw0, sw1, sw2, l);
        fft_inv_k  <<<NB * NH / 2, 256, 0, stream>>>(Y2p, Y1p, Y0p, sbuf, tw,
                                                     sb0, sb1, sb2, l);
        conv_fused_k<<<(NB * LEN) / 256, 256, 0, stream>>>(sbuf, conv1w, conv1b,
                                                           w2tb, conv2b, l, vbuf,
                                                           dec_w, dec_b, (float*)d_out,
                                                           l == NLAYER - 1);
    }
}

// Round 11
// 1148.561 us; speedup vs baseline: 1.1887x; 1.0790x over previous
//
#include <hip/hip_runtime.h>
#include <math.h>

#ifndef M_PI
#define M_PI 3.14159265358979323846
#endif

#define LEN   4096
#define NB    32
#define NH    64
#define NF    2048   // modes stored (bins 0..2047)
#define NLAYER 4

__device__ __forceinline__ float2 cmul(float2 a, float2 b) {
    return make_float2(a.x*b.x - a.y*b.y, a.x*b.y + a.y*b.x);
}

// powers W[k] = w1^k, k=0..15, via squaring ladder (max 3 chained muls)
__device__ __forceinline__ void twpow16(float2 w1, float2 W[16]) {
    W[0] = make_float2(1.0f, 0.0f);
    W[1] = w1;
    W[2] = cmul(w1, w1);
    W[3] = cmul(W[2], W[1]);
    W[4] = cmul(W[2], W[2]);
    W[5] = cmul(W[4], W[1]);
    W[6] = cmul(W[4], W[2]);
    W[7] = cmul(W[4], W[3]);
    W[8] = cmul(W[4], W[4]);
    W[9]  = cmul(W[8], W[1]);
    W[10] = cmul(W[8], W[2]);
    W[11] = cmul(W[8], W[3]);
    W[12] = cmul(W[8], W[4]);
    W[13] = cmul(W[8], W[5]);
    W[14] = cmul(W[8], W[6]);
    W[15] = cmul(W[8], W[7]);
}

// async global -> LDS, 16 B per lane (dest = wave-uniform base + lane*16)
__device__ __forceinline__ void gll16(const void* g, void* l) {
    __builtin_amdgcn_global_load_lds(
        (const __attribute__((address_space(1))) void*)g,
        (__attribute__((address_space(3))) void*)l, 16, 0, 0);
}

// ---------------------------------------------------------------------------
// twiddle table: tw[k] = exp(-2*pi*i*k/4096), k = 0..4095 (full circle)
__global__ __launch_bounds__(256) void fill_tw(float2* __restrict__ tw) {
    int k = blockIdx.x * 256 + threadIdx.x;
    if (k < 4096) {
        double ang = -2.0 * M_PI * (double)k / 4096.0;
        tw[k] = make_float2((float)cos(ang), (float)sin(ang));
    }
}

// ---------------------------------------------------------------------------
// conv2 weight transpose: w2t[l][i][o] = w2[l][o][i]  (4 layers x 64 x 64)
__global__ __launch_bounds__(256) void w2t_k(
        const float* __restrict__ w2, float* __restrict__ w2t) {
    int idx = blockIdx.x * 256 + threadIdx.x;    // 0..16383
    int l = idx >> 12;
    int r = idx & 4095;
    int o = r >> 6, i = r & 63;
    w2t[l * 4096 + i * 64 + o] = w2[idx];
}

// ---------------------------------------------------------------------------
// in-register 16-point DIF FFT. Natural-order input z[n]; output Z[k] lands
// in z[BR16[k]] (4-bit reversal, compile-time). INV=true: conjugated twiddles.
#define BR16_INIT const int BR[16] = {0,8,4,12,2,10,6,14,1,9,5,13,3,11,7,15}

template<bool INV>
__device__ __forceinline__ void fft16(float2 z[16]) {
    const float S  = INV ? 1.0f : -1.0f;
    const float C1 = 0.9238795325112867f, S1 = 0.3826834323650898f;
    const float C2 = 0.7071067811865476f;
    const float2 W16[8] = {{1.f,0.f},{C1,S*S1},{C2,S*C2},{S1,S*C1},
                           {0.f,S},{-S1,S*C1},{-C2,S*C2},{-C1,S*S1}};
    const float2 W8[4]  = {{1.f,0.f},{C2,S*C2},{0.f,S},{-C2,S*C2}};
    #pragma unroll
    for (int i = 0; i < 8; ++i) {
        float2 u = z[i], v = z[i+8];
        z[i]   = make_float2(u.x+v.x, u.y+v.y);
        float2 d = make_float2(u.x-v.x, u.y-v.y);
        z[i+8] = cmul(d, W16[i]);
    }
    #pragma unroll
    for (int h = 0; h < 16; h += 8)
        #pragma unroll
        for (int i = 0; i < 4; ++i) {
            float2 u = z[h+i], v = z[h+i+4];
            z[h+i]   = make_float2(u.x+v.x, u.y+v.y);
            float2 d = make_float2(u.x-v.x, u.y-v.y);
            z[h+i+4] = cmul(d, W8[i]);
        }
    #pragma unroll
    for (int h = 0; h < 16; h += 4) {
        { float2 u = z[h],   v = z[h+2];
          z[h]   = make_float2(u.x+v.x, u.y+v.y);
          z[h+2] = make_float2(u.x-v.x, u.y-v.y); }
        { float2 u = z[h+1], v = z[h+3];
          z[h+1] = make_float2(u.x+v.x, u.y+v.y);
          float2 d = make_float2(u.x-v.x, u.y-v.y);
          z[h+3] = make_float2(-S*d.y, S*d.x); }      // d * (0,S)
    }
    #pragma unroll
    for (int h = 0; h < 16; h += 2) {
        float2 u = z[h], v = z[h+1];
        z[h]   = make_float2(u.x+v.x, u.y+v.y);
        z[h+1] = make_float2(u.x-v.x, u.y-v.y);
    }
}

// ---------------------------------------------------------------------------
// encoder
__global__ __launch_bounds__(256) void encoder_k(
        const float* __restrict__ x, const float* __restrict__ u,
        const float* __restrict__ ew, const float* __restrict__ eb,
        float* __restrict__ v) {
    int tid = blockIdx.x * 256 + threadIdx.x;
    int b = tid >> 12;
    int l = tid & (LEN - 1);
    float xv = x[(size_t)b * LEN + l];
    float u0 = u[((size_t)b * 3 + 0) * LEN + l];
    float u1 = u[((size_t)b * 3 + 1) * LEN + l];
    float u2 = u[((size_t)b * 3 + 2) * LEN + l];
    for (int h = 0; h < NH; ++h) {
        float a = eb[h] + ew[h*4+0]*xv + ew[h*4+1]*u0 + ew[h*4+2]*u1 + ew[h*4+3]*u2;
        v[((size_t)b * NH + h) * LEN + l] = a;
    }
}

// ---------------------------------------------------------------------------
// forward FFT, radix-16^3 four-step. Twiddles GATHER-FREE: one coalesced
// tw[t] + squaring ladder replaces 15 strided gathers (the R6-R10 hidden
// cost: ~120 cachelines per gather through the CU's single TA).
__global__ __launch_bounds__(256) void fft_fwd_k(
        const float* __restrict__ vin, float2* __restrict__ Xt,
        const float2* __restrict__ tw) {
    __shared__ float2 lds[4352];                 // 34816 B
    BR16_INIT;
    int p = blockIdx.x;                          // 0..1023
    const float* s1 = vin + (size_t)(2*p)   * LEN;
    const float* s2 = vin + (size_t)(2*p+1) * LEN;
    int t = threadIdx.x;                         // = b
    float2 z[16];
    #pragma unroll
    for (int a = 0; a < 16; ++a)
        z[a] = make_float2(s1[a*256 + t], s2[a*256 + t]);
    fft16<false>(z);
    {
        float2 Wp[16];
        twpow16(tw[t], Wp);                      // W4096^(t*ka), coalesced base
        #pragma unroll
        for (int r = 0; r < 16; ++r) {
            int ka = BR[r];
            lds[ka*256 + t] = cmul(z[r], Wp[ka]);
        }
    }
    __syncthreads();
    int ka = t >> 4, bp = t & 15;                // round-2 role (k_a, b')
    #pragma unroll
    for (int a2 = 0; a2 < 16; ++a2)
        z[a2] = lds[ka*256 + a2*16 + bp];        // b = a2*16 + b'
    __syncthreads();
    fft16<false>(z);
    {
        float2 Wq[16];
        twpow16(tw[16*bp], Wq);                  // W256^(bp*kap), 16-bcast base
        #pragma unroll
        for (int r = 0; r < 16; ++r) {
            int kap = BR[r];
            lds[kap*272 + ka*17 + bp] = cmul(z[r], Wq[kap]);
        }
    }
    __syncthreads();
    int kap2 = t >> 4, ka2 = t & 15;             // round-3 role (k_a', k_a)
    #pragma unroll
    for (int b2 = 0; b2 < 16; ++b2)
        z[b2] = lds[kap2*272 + ka2*17 + b2];
    __syncthreads();
    fft16<false>(z);
    #pragma unroll
    for (int r = 0; r < 16; ++r)
        lds[t + 256*BR[r]] = z[r];
    __syncthreads();
    float2* d1 = Xt + (size_t)(2*p)   * NF;
    float2* d2 = Xt + (size_t)(2*p+1) * NF;
    for (int j = 0; j < 8; ++j) {
        int f = t + j * 256;                     // 0..2047
        float2 Zf = lds[f];
        float2 Zm = lds[(4096 - f) & 4095];
        d1[f] = make_float2(0.5f * (Zf.x + Zm.x), 0.5f * (Zf.y - Zm.y));
        d2[f] = make_float2(0.5f * (Zf.y + Zm.y), 0.5f * (Zm.x - Zf.x));
    }
}

// ---------------------------------------------------------------------------
// inverse FFT, radix-16^3 four-step, gather-free twiddles (conjugated base).
__device__ __forceinline__ float2 load_partial(
        const float2* __restrict__ r2, const float2* __restrict__ r1,
        const float2* __restrict__ r0, int f) {
    float2 y = r2[f];
    if (f < 1024) {
        float2 q = r1[f]; y.x += q.x; y.y += q.y;
        if (f < 512) { float2 w = r0[f]; y.x += w.x; y.y += w.y; }
    }
    return y;
}

__global__ __launch_bounds__(256) void fft_inv_k(
        const float2* __restrict__ Y2, const float2* __restrict__ Y1,
        const float2* __restrict__ Y0, float* __restrict__ sout,
        const float2* __restrict__ tw,
        const float* __restrict__ sb0, const float* __restrict__ sb1,
        const float* __restrict__ sb2, int layer) {
    __shared__ float2 lds[4352];
    BR16_INIT;
    int p = blockIdx.x;                          // 0..1023
    int o = (2 * p) & (NH - 1);                  // even o
    const float2* r1_2 = Y2 + (size_t)(2*p)   * 2048;
    const float2* r2_2 = Y2 + (size_t)(2*p+1) * 2048;
    const float2* r1_1 = Y1 + (size_t)(2*p)   * 1024;
    const float2* r2_1 = Y1 + (size_t)(2*p+1) * 1024;
    const float2* r1_0 = Y0 + (size_t)(2*p)   * 512;
    const float2* r2_0 = Y0 + (size_t)(2*p+1) * 512;
    int t = threadIdx.x;
    float2 z[16];
    #pragma unroll
    for (int a = 0; a < 16; ++a) {
        int f = a * 256 + t;
        float2 zf;
        if (f < 2048) {
            float2 y1 = load_partial(r1_2, r1_1, r1_0, f);
            float2 y2 = load_partial(r2_2, r2_1, r2_0, f);
            if (f == 0) zf = make_float2(y1.x, y2.x);
            else        zf = make_float2(y1.x - y2.y, y1.y + y2.x);
        } else if (f == 2048) {
            zf = make_float2(0.0f, 0.0f);
        } else {
            int m = 4096 - f;                    // 1..2047
            float2 y1 = load_partial(r1_2, r1_1, r1_0, m);
            float2 y2 = load_partial(r2_2, r2_1, r2_0, m);
            zf = make_float2(y1.x + y2.y, y2.x - y1.y);  // conj(Y1)+i*conj(Y2)
        }
        z[a] = zf;
    }
    fft16<true>(z);
    {
        float2 w1 = tw[t]; w1.y = -w1.y;         // conj base -> conj powers
        float2 Wp[16];
        twpow16(w1, Wp);
        #pragma unroll
        for (int r = 0; r < 16; ++r) {
            int ka = BR[r];
            lds[ka*256 + t] = cmul(z[r], Wp[ka]);
        }
    }
    __syncthreads();
    int ka = t >> 4, bp = t & 15;
    #pragma unroll
    for (int a2 = 0; a2 < 16; ++a2)
        z[a2] = lds[ka*256 + a2*16 + bp];
    __syncthreads();
    fft16<true>(z);
    {
        float2 w16 = tw[16*bp]; w16.y = -w16.y;
        float2 Wq[16];
        twpow16(w16, Wq);
        #pragma unroll
        for (int r = 0; r < 16; ++r) {
            int kap = BR[r];
            lds[kap*272 + ka*17 + bp] = cmul(z[r], Wq[kap]);
        }
    }
    __syncthreads();
    int kap2 = t >> 4, ka2 = t & 15;
    #pragma unroll
    for (int b2 = 0; b2 < 16; ++b2)
        z[b2] = lds[kap2*272 + ka2*17 + b2];
    fft16<true>(z);
    float bias1 = sb0[layer*NH+o]   + sb1[layer*NH+o]   + sb2[layer*NH+o];
    float bias2 = sb0[layer*NH+o+1] + sb1[layer*NH+o+1] + sb2[layer*NH+o+1];
    float* d1 = sout + (size_t)(2*p)   * LEN;
    float* d2 = sout + (size_t)(2*p+1) * LEN;
    const float sc = 1.0f / 4096.0f;
    #pragma unroll
    for (int r = 0; r < 16; ++r) {
        int l = t + 256 * BR[r];
        d1[l] = z[r].x * sc + bias1;
        d2[l] = z[r].y * sc + bias2;
    }
}

// ---------------------------------------------------------------------------
// spectral matmul v8 (round-9 verified): v7 ring + XCD-resident sibling groups.
__global__ __launch_bounds__(256) void specmm_k(
        const float2* __restrict__ X,
        float2* __restrict__ Y2p, float2* __restrict__ Y1p, float2* __restrict__ Y0p,
        const float* __restrict__ w0, const float* __restrict__ w1,
        const float* __restrict__ w2, int layer) {
    __shared__ float2 Xb[3][1024];    // [buf][i4][b32][slot4][e2]  8 KB each
    __shared__ float2 Wb[3][512];     // [buf][i4][o16][slot4][e2]  4 KB each

    int n   = blockIdx.x;             // 0..1791
    int xcd = n & 7;                  // dispatch round-robin -> XCD id
    int s   = n >> 3;                 // slot within XCD, 0..223
    int k, ftile, og;
    if (s < 96) {            // heavy: f0 < 512, 3 streams x 4 og = 12 sibs
        int h = s / 12, sib = s - h * 12;
        ftile = xcd * 8 + h;                    // 0..63
        og = sib & 3;  k = sib >> 2;            // k in {0,1,2}
    } else if (s < 160) {    // medium: 512 <= f0 < 1024, 2 streams x 4 og
        int m = (s - 96) >> 3, sib = (s - 96) & 7;
        ftile = 64 + xcd * 8 + m;               // 64..127
        og = sib & 3;  k = 2 - (sib >> 2);      // k in {2,1}
    } else {                 // light: f0 >= 1024, 1 stream x 4 og
        int l2 = (s - 160) >> 2, sib = (s - 160) & 3;
        ftile = 128 + xcd * 16 + l2;            // 128..255
        og = sib;      k = 2;
    }
    int f0 = ftile * 8;

    const float2* wbp; float2* Yb; size_t mk;
    if (k == 2)      { wbp = (const float2*)w2 + (size_t)layer*NH*NH*2048; Yb = Y2p; mk = 2048; }
    else if (k == 1) { wbp = (const float2*)w1 + (size_t)layer*NH*NH*1024; Yb = Y1p; mk = 1024; }
    else             { wbp = (const float2*)w0 + (size_t)layer*NH*NH*512;  Yb = Y0p; mk = 512;  }

    int t  = threadIdx.x;
    int ff = t & 7;                   // compute: f offset 0..7
    int u  = t >> 3;                  // 0..31
    int b0  = (u & 7) * 4;            // compute: 4 b rows
    int oo0 = (u >> 3) * 4;           // compute: 4 o cols (== wave id)

    // staging roles: wave wv stages i-row wv of each 4-i chunk
    const int wv = t >> 6;            // wave 0..3
    const int ln = t & 63;
    const int bs = ln >> 2;           // 0..15 (b-sub / o)
    const int sl = ln & 3;            // slot 0..3

    float2 acc[4][4];
    #pragma unroll
    for (int bb = 0; bb < 4; ++bb)
        #pragma unroll
        for (int oo = 0; oo < 4; ++oo)
            acc[bb][oo] = make_float2(0.0f, 0.0f);

    // per-lane global source pointers (X pre-swizzled)
    const float2* gx0; const float2* gx1;
    {
        int b = bs;                                    // half 0
        int fp = sl ^ ((b >> 2) & 3);
        gx0 = X + ((size_t)b * NH + wv) * 2048 + f0 + 2*fp;
        b = 16 + bs;                                   // half 1
        fp = sl ^ ((b >> 2) & 3);
        gx1 = X + ((size_t)b * NH + wv) * 2048 + f0 + 2*fp;
    }
    const float2* gw = wbp + ((size_t)wv * NH + og*16 + bs) * mk + f0 + 2*sl;

    #define STAGE(ic_, nb_)                                                     \
    {                                                                           \
        gll16(gx0 + (size_t)(ic_)*4*2048, &Xb[nb_][(wv*32 +  0)*8]);            \
        gll16(gx1 + (size_t)(ic_)*4*2048, &Xb[nb_][(wv*32 + 16)*8]);            \
        gll16(gw  + (size_t)(ic_)*256*mk, &Wb[nb_][wv*128]);                    \
    }

    STAGE(0, 0);
    STAGE(1, 1);
    STAGE(2, 2);
    int cb = 0;
    for (int ic = 0; ic < 16; ++ic) {
        // counted wait: oldest chunk's 3 loads landed; rest stay in flight
        if (ic < 14)       asm volatile("s_waitcnt vmcnt(6)" ::: "memory");
        else if (ic == 14) asm volatile("s_waitcnt vmcnt(3)" ::: "memory");
        else               asm volatile("s_waitcnt vmcnt(0)" ::: "memory");
        __builtin_amdgcn_sched_barrier(0);
        __builtin_amdgcn_s_barrier();             // all waves' DMAs complete
        #pragma unroll
        for (int ii = 0; ii < 4; ++ii) {
            float2 xr[4], wr[4];
            #pragma unroll
            for (int bb = 0; bb < 4; ++bb) {
                int b = b0 + bb;
                int slot = (ff >> 1) ^ ((b >> 2) & 3);
                xr[bb] = Xb[cb][((ii*32 + b)*4 + slot)*2 + (ff & 1)];
            }
            #pragma unroll
            for (int oo = 0; oo < 4; ++oo)
                wr[oo] = Wb[cb][((ii*16 + oo0 + oo)*4 + (ff >> 1))*2 + (ff & 1)];
            #pragma unroll
            for (int bb = 0; bb < 4; ++bb)
                #pragma unroll
                for (int oo = 0; oo < 4; ++oo) {
                    acc[bb][oo].x += xr[bb].x * wr[oo].x - xr[bb].y * wr[oo].y;
                    acc[bb][oo].y += xr[bb].x * wr[oo].y + xr[bb].y * wr[oo].x;
                }
        }
        __builtin_amdgcn_s_barrier();             // buf[cb] free to overwrite
        if (ic < 13) STAGE(ic + 3, cb);           // lands ~2 chunks later
        cb = (cb == 2) ? 0 : cb + 1;
    }
    #undef STAGE

    // direct coalesced stores (lanes ff-contiguous -> 64B f-runs)
    #pragma unroll
    for (int bb = 0; bb < 4; ++bb)
        #pragma unroll
        for (int oo = 0; oo < 4; ++oo)
            Yb[((size_t)(b0 + bb) * NH + og * 16 + oo0 + oo) * mk + f0 + ff] = acc[bb][oo];
}

// ---------------------------------------------------------------------------
// fused conv1+gelu+conv2+residual v2 (round-10 verified): 4-acc conv1 dot,
// pre-transposed w2t rows. Last layer: decoder fused, writes out directly.
__global__ __launch_bounds__(256) void conv_fused_k(
        const float* __restrict__ s,
        const float* __restrict__ c1w, const float* __restrict__ c1b,
        const float* __restrict__ w2t, const float* __restrict__ c2b,
        int layer, float* __restrict__ v,
        const float* __restrict__ dw, const float* __restrict__ db,
        float* __restrict__ out, int last) {
    int tid = blockIdx.x * 256 + threadIdx.x;
    int b = tid >> 12;
    int l = tid & (LEN - 1);
    float xr[NH];
    #pragma unroll
    for (int i = 0; i < NH; ++i) xr[i] = s[((size_t)b * NH + i) * LEN + l];
    const float* w1 = c1w + (size_t)layer * NH * NH;
    const float* b1 = c1b + layer * NH;
    const float* w2 = w2t + (size_t)layer * NH * NH;   // [i][o] rows
    const float* b2 = c2b + layer * NH;
    float acc2[NH];
    #pragma unroll
    for (int o = 0; o < NH; ++o) acc2[o] = b2[o];
    for (int i = 0; i < NH; ++i) {               // not unrolled: keeps I-size sane
        const float* wr = w1 + i * NH;
        float a0 = 0.0f, a1 = 0.0f, a2 = 0.0f, a3 = 0.0f;
        #pragma unroll
        for (int k = 0; k < NH; k += 4) {
            a0 += wr[k]     * xr[k];
            a1 += wr[k + 1] * xr[k + 1];
            a2 += wr[k + 2] * xr[k + 2];
            a3 += wr[k + 3] * xr[k + 3];
        }
        float acc = b1[i] + ((a0 + a1) + (a2 + a3));
        float cc = 0.7978845608028654f * (acc + 0.044715f * acc * acc * acc);
        float e  = __expf(2.0f * cc);
        float th = 1.0f - 2.0f / (e + 1.0f);
        float h  = 0.5f * acc * (1.0f + th);
        const float* wc = w2 + i * NH;
        #pragma unroll
        for (int o = 0; o < NH; ++o) acc2[o] += wc[o] * h;
    }
    if (!last) {
        #pragma unroll
        for (int o = 0; o < NH; ++o) {
            size_t idx = ((size_t)b * NH + o) * LEN + l;
            v[idx] = v[idx] + acc2[o];
        }
    } else {
        float acc = db[0];
        #pragma unroll
        for (int o = 0; o < NH; ++o) {
            size_t idx = ((size_t)b * NH + o) * LEN + l;
            acc += dw[o] * (v[idx] + acc2[o]);
        }
        out[(size_t)b * LEN + l] = acc;
    }
}

// ---------------------------------------------------------------------------
extern "C" void kernel_launch(void* const* d_in, const int* in_sizes, int n_in,
                              void* d_out, int out_size, void* d_ws, size_t ws_size,
                              hipStream_t stream) {
    const float* u_in   = (const float*)d_in[0];
    const float* x_in   = (const float*)d_in[1];
    const float* enc_w  = (const float*)d_in[2];
    const float* enc_b  = (const float*)d_in[3];
    const float* dec_w  = (const float*)d_in[4];
    const float* dec_b  = (const float*)d_in[5];
    const float* conv1w = (const float*)d_in[6];
    const float* conv1b = (const float*)d_in[7];
    const float* conv2w = (const float*)d_in[8];
    const float* conv2b = (const float*)d_in[9];
    const float* sw0    = (const float*)d_in[10];
    const float* sb0    = (const float*)d_in[11];
    const float* sw1    = (const float*)d_in[12];
    const float* sb1    = (const float*)d_in[13];
    const float* sw2    = (const float*)d_in[14];
    const float* sb2    = (const float*)d_in[15];

    const size_t CPLX = (size_t)2048 * 2048;
    const size_t REAL = (size_t)NB * NH * LEN;
    char* base = (char*)d_ws;
    float2* tw   = (float2*)base;                // 4096 entries = 32768 B
    float2* bufA = (float2*)(base + 32768);      // X: [row][2048]
    float2* Y2p  = bufA + CPLX;                  // [row][2048]
    float2* Y1p  = Y2p + CPLX;                   // [row][1024]
    float2* Y0p  = Y1p + (size_t)2048 * 1024;    // [row][512]
    float*  sbuf = (float*)(Y0p + (size_t)2048 * 512);
    float*  vbuf = sbuf + REAL;
    float*  w2tb = vbuf + REAL;                  // transposed conv2 weights, 64 KB
    size_t need = 32768 + (CPLX + CPLX + (size_t)2048*1024 + (size_t)2048*512) * sizeof(float2)
                + 2 * REAL * sizeof(float) + (size_t)NLAYER*NH*NH*sizeof(float);
    if (ws_size < need) return;

    fill_tw<<<16, 256, 0, stream>>>(tw);
    w2t_k<<<64, 256, 0, stream>>>(conv2w, w2tb);
    encoder_k<<<(NB * LEN) / 256, 256, 0, stream>>>(x_in, u_in, enc_w, enc_b, vbuf);

    for (int l = 0; l < NLAYER; ++l) {
        fft_fwd_k  <<<NB * NH / 2, 256, 0, stream>>>(vbuf, bufA, tw);
        specmm_k   <<<1792, 256, 0, stream>>>(bufA, Y2p, Y1p, Y0p, sw0, sw1, sw2, l);
        fft_inv_k  <<<NB * NH / 2, 256, 0, stream>>>(Y2p, Y1p, Y0p, sbuf, tw,
                                                     sb0, sb1, sb2, l);
        conv_fused_k<<<(NB * LEN) / 256, 256, 0, stream>>>(sbuf, conv1w, conv1b,
                                                           w2tb, conv2b, l, vbuf,
                                                           dec_w, dec_b, (float*)d_out,
                                                           l == NLAYER - 1);
    }
}